// Round 2
// baseline (62.769 us; speedup 1.0000x reference)
//
#include <hip/hip_runtime.h>

#define KERNEL_LEN 128
#define INPUT_LEN 1000000
#define PATH_NUM 10
#define L_TOTAL (INPUT_LEN + KERNEL_LEN)
#define BLOCKS_PER_PATH 128
#define BLOCK_SIZE 256
#define CHUNK 16   // elements per thread per loop iteration

typedef int v4i __attribute__((ext_vector_type(4)));

__global__ __launch_bounds__(BLOCK_SIZE) void dtw_spring_npath_kernel(
    const float* __restrict__ kern,
    const float* __restrict__ x,
    const int*   __restrict__ path_k,
    const int*   __restrict__ path_i,
    const int*   __restrict__ path_length,
    const int*   __restrict__ path_num,
    float*       __restrict__ out)
{
    __shared__ float k_lds[KERNEL_LEN];
    const int tid = threadIdx.x;
    if (tid < KERNEL_LEN) k_lds[tid] = kern[tid];
    __syncthreads();

    const int p = blockIdx.y;
    const int n = min(path_num[0], PATH_NUM);
    if (p >= n) return;                 // block-uniform exit; out already zeroed

    const int len  = path_length[p];
    const int lenC = len & ~(CHUNK - 1);

    const int* __restrict__ pk = path_k + (size_t)p * L_TOTAL;
    const int* __restrict__ pi = path_i + (size_t)p * L_TOTAL;

    float acc = 0.0f;
    const int stride = gridDim.x * BLOCK_SIZE * CHUNK;
    for (int t0 = (blockIdx.x * BLOCK_SIZE + tid) * CHUNK; t0 < lenC; t0 += stride) {
        // 16 elements: 4+4 coalesced dwordx4 index loads (nontemporal: read-once
        // streams, keep them from evicting x's gather working set out of L2),
        // then 16 independent gathers in flight.
        const v4i* pk4 = reinterpret_cast<const v4i*>(pk + t0);
        const v4i* pi4 = reinterpret_cast<const v4i*>(pi + t0);
        v4i ik[4], ii[4];
        #pragma unroll
        for (int c = 0; c < 4; ++c) ik[c] = __builtin_nontemporal_load(pk4 + c);
        #pragma unroll
        for (int c = 0; c < 4; ++c) ii[c] = __builtin_nontemporal_load(pi4 + c);

        float xs[CHUNK];
        #pragma unroll
        for (int c = 0; c < 4; ++c) {
            #pragma unroll
            for (int j = 0; j < 4; ++j)
                xs[c * 4 + j] = x[(unsigned)ii[c][j]];   // 32-bit offset -> saddr form
        }
        #pragma unroll
        for (int c = 0; c < 4; ++c) {
            #pragma unroll
            for (int j = 0; j < 4; ++j) {
                const float d = k_lds[(unsigned)ik[c][j]] - xs[c * 4 + j];
                acc = fmaf(d, d, acc);
            }
        }
    }
    // tail (< 16 elements), handled by block x==0 only
    if (blockIdx.x == 0) {
        const int t = lenC + tid;
        if (t < len) {
            const float d = k_lds[pk[t]] - x[pi[t]];
            acc = fmaf(d, d, acc);
        }
    }

    // wave (64-lane) reduction
    #pragma unroll
    for (int off = 32; off > 0; off >>= 1)
        acc += __shfl_down(acc, off, 64);

    __shared__ float wsum[BLOCK_SIZE / 64];
    const int wave = tid >> 6;
    if ((tid & 63) == 0) wsum[wave] = acc;
    __syncthreads();
    if (tid == 0) {
        const float s = wsum[0] + wsum[1] + wsum[2] + wsum[3];
        atomicAdd(&out[p], s);
    }
}

extern "C" void kernel_launch(void* const* d_in, const int* in_sizes, int n_in,
                              void* d_out, int out_size, void* d_ws, size_t ws_size,
                              hipStream_t stream) {
    const float* kern        = (const float*)d_in[0];
    const float* x           = (const float*)d_in[1];
    const int*   path_k      = (const int*)d_in[2];
    const int*   path_i      = (const int*)d_in[3];
    const int*   path_length = (const int*)d_in[4];
    const int*   path_num    = (const int*)d_in[5];
    float*       out         = (float*)d_out;

    hipMemsetAsync(out, 0, (size_t)out_size * sizeof(float), stream);

    dim3 grid(BLOCKS_PER_PATH, PATH_NUM);
    dim3 block(BLOCK_SIZE);
    dtw_spring_npath_kernel<<<grid, block, 0, stream>>>(
        kern, x, path_k, path_i, path_length, path_num, out);
}

// Round 3
// 53.833 us; speedup vs baseline: 1.1660x; 1.1660x over previous
//
#include <hip/hip_runtime.h>

#define KERNEL_LEN 128
#define INPUT_LEN 1000000
#define PATH_NUM 10
#define L_TOTAL (INPUT_LEN + KERNEL_LEN)
#define NBLOCKS 2048
#define BLOCK_SIZE 256
#define CHUNK 4

typedef int v4i __attribute__((ext_vector_type(4)));

__global__ __launch_bounds__(BLOCK_SIZE) void dtw_spring_npath_kernel(
    const float* __restrict__ kern,
    const float* __restrict__ x,
    const int*   __restrict__ path_k,
    const int*   __restrict__ path_i,
    const int*   __restrict__ path_length,
    const int*   __restrict__ path_num,
    float*       __restrict__ out)
{
    __shared__ float k_lds[KERNEL_LEN];
    const int tid = threadIdx.x;
    if (tid < KERNEL_LEN) k_lds[tid] = kern[tid];
    __syncthreads();

    const int n = min(path_num[0], PATH_NUM);

    float acc[PATH_NUM];
    #pragma unroll
    for (int p = 0; p < PATH_NUM; ++p) acc[p] = 0.0f;

    const int start  = (blockIdx.x * BLOCK_SIZE + tid) * CHUNK;
    const int stride = NBLOCKS * BLOCK_SIZE * CHUNK;   // 2M > L: usually 1 iter/path

    #pragma unroll
    for (int p = 0; p < PATH_NUM; ++p) {
        if (p < n) {                                   // uniform guard (no break: keep unroll clean)
            const int len  = path_length[p];
            const int len4 = len & ~(CHUNK - 1);
            const int* __restrict__ pk = path_k + (size_t)p * L_TOTAL;
            const int* __restrict__ pi = path_i + (size_t)p * L_TOTAL;

            float a = 0.0f;
            for (int t = start; t < len4; t += stride) {
                // lane i reads 16B at lane*16B -> 1KB coalesced wave segment
                const v4i ik = *reinterpret_cast<const v4i*>(pk + t);
                const v4i ii = *reinterpret_cast<const v4i*>(pi + t);
                const float x0 = x[(unsigned)ii[0]];
                const float x1 = x[(unsigned)ii[1]];
                const float x2 = x[(unsigned)ii[2]];
                const float x3 = x[(unsigned)ii[3]];
                const float d0 = k_lds[(unsigned)ik[0]] - x0;
                const float d1 = k_lds[(unsigned)ik[1]] - x1;
                const float d2 = k_lds[(unsigned)ik[2]] - x2;
                const float d3 = k_lds[(unsigned)ik[3]] - x3;
                a = fmaf(d0, d0, a);
                a = fmaf(d1, d1, a);
                a = fmaf(d2, d2, a);
                a = fmaf(d3, d3, a);
            }
            // tail (< 4 elements): block 0 only
            if (blockIdx.x == 0) {
                const int t = len4 + tid;
                if (t < len) {
                    const float d = k_lds[pk[t]] - x[pi[t]];
                    a = fmaf(d, d, a);
                }
            }
            acc[p] = a;
        }
    }

    // per-wave reduce all paths, then cross-wave via LDS
    __shared__ float wsum[PATH_NUM][BLOCK_SIZE / 64];
    const int wave = tid >> 6;
    const int lane = tid & 63;
    #pragma unroll
    for (int p = 0; p < PATH_NUM; ++p) {
        float a = acc[p];
        #pragma unroll
        for (int off = 32; off > 0; off >>= 1)
            a += __shfl_down(a, off, 64);
        if (lane == 0) wsum[p][wave] = a;
    }
    __syncthreads();
    if (tid < PATH_NUM && tid < n) {
        const float s = wsum[tid][0] + wsum[tid][1] + wsum[tid][2] + wsum[tid][3];
        if (s != 0.0f) atomicAdd(&out[tid], s);   // skip: blocks past this path's end
    }
}

extern "C" void kernel_launch(void* const* d_in, const int* in_sizes, int n_in,
                              void* d_out, int out_size, void* d_ws, size_t ws_size,
                              hipStream_t stream) {
    const float* kern        = (const float*)d_in[0];
    const float* x           = (const float*)d_in[1];
    const int*   path_k      = (const int*)d_in[2];
    const int*   path_i      = (const int*)d_in[3];
    const int*   path_length = (const int*)d_in[4];
    const int*   path_num    = (const int*)d_in[5];
    float*       out         = (float*)d_out;

    hipMemsetAsync(out, 0, (size_t)out_size * sizeof(float), stream);

    dtw_spring_npath_kernel<<<dim3(NBLOCKS), dim3(BLOCK_SIZE), 0, stream>>>(
        kern, x, path_k, path_i, path_length, path_num, out);
}